// Round 10
// baseline (523.991 us; speedup 1.0000x reference)
//
#include <hip/hip_runtime.h>
#include <math.h>

// SwarmSetEquivariantTorso — bf16 MFMA, N-split block-coop GEMMs + REGISTER
// WEIGHT PREFETCH. Block = 256 / 4 waves / 12 tokens (60 slot rows, 4 M-tiles).
// Wave wv owns N-tile columns; weight fragments loaded ONCE per block from the
// pre-transposed bf16 W_t[n][k] image (d_ws) — and now loaded ONE PHASE EARLY
// into registers, so the post-barrier load latency overlaps the previous
// phase's compute (the __syncthreads vmcnt(0) drain makes in-phase loads fully
// exposed otherwise; compiler can't hoist loads across the barrier intrinsic).

#define DOBS 198
#define NEG_INF_F (-3.402823466e38f)

typedef __bf16 v8bf __attribute__((ext_vector_type(8)));
typedef __bf16 v4bf __attribute__((ext_vector_type(4)));
typedef float  v4f  __attribute__((ext_vector_type(4)));

struct P {
  const float *obs,*tok_w,*tok_b,*ln1_s,*ln1_b,
    *a1_qw,*a1_qb,*a1_kw,*a1_kb,*a1_vw,*a1_vb,*a1_ow,*a1_ob,
    *ln2_s,*ln2_b,*m1_w,*m1_b,*m2_w,*m2_b,*m3_w,*m3_b,
    *e1_w,*e1_b,*e2_w,*e2_b,*e3_w,*e3_b,
    *l1_w,*l1_b,*l2_w,*l2_b,*l3_w,*l3_b,
    *seed,*p_qw,*p_qb,*p_kw,*p_kb,*p_vw,*p_vb,*p_ow,*p_ob,
    *pr_w,*pr_b,*h1_w,*h1_b,*h2_w,*h2_b,*h3_w,*h3_b;
  float* out;
};
static_assert(sizeof(P) == 51*sizeof(void*), "P layout");

// ws bf16 weight image, W_t[n][k] per matrix (element offsets)
#define W_A1Q 0
#define W_A1K 4096
#define W_A1V 8192
#define W_A1O 12288
#define W_M1  16384
#define W_M2  24576
#define W_M3  40960
#define W_E1  49152
#define W_E2  53248
#define W_E3  69632
#define W_L1  77824
#define W_L2  94208
#define W_PK  110592
#define W_PV  114688
#define W_PO  118784
#define W_H1  122880
#define W_H2  143360
#define W_H3  159744
#define W_END 176128
#define W_QP  176128   // + 64 f32 (pooling query, precomputed)

__global__ __launch_bounds__(256)
void prep_w(P a, __bf16* ws)
{
  if (blockIdx.x == 172){
    int t = threadIdx.x;
    if (t < 64){
      float acc = a.p_qb[t];
      for (int k=0;k<64;k++) acc += a.seed[k]*a.p_qw[k*64+t];
      ((float*)(ws + W_QP))[t] = acc;
    }
    return;
  }
  const float* srcs[18] = {a.a1_qw,a.a1_kw,a.a1_vw,a.a1_ow,a.m1_w,a.m2_w,a.m3_w,
                           a.e1_w,a.e2_w,a.e3_w,a.l1_w,a.l2_w,a.p_kw,a.p_vw,a.p_ow,
                           a.h1_w,a.h2_w,a.h3_w};
  const int Ks[18]   = {64,64,64,64,64,128,128,32,128,128,128,128,64,64,64,160,128,128};
  const int Ns[18]   = {64,64,64,64,128,128,64,128,128,64,128,128,64,64,64,128,128,128};
  const int offs[18] = {W_A1Q,W_A1K,W_A1V,W_A1O,W_M1,W_M2,W_M3,W_E1,W_E2,W_E3,
                        W_L1,W_L2,W_PK,W_PV,W_PO,W_H1,W_H2,W_H3};
  __shared__ float tile[32][33];
  int b = blockIdx.x, m = 0, acc = 0;
  for (; m < 18; m++){
    int t = (Ks[m]/32)*(Ns[m]/32);
    if (b < acc + t) break;
    acc += t;
  }
  int lt = b - acc, K = Ks[m], N = Ns[m];
  int ntile = N/32, kt = lt/ntile, nt = lt%ntile;
  int tx = threadIdx.x & 31, ty = threadIdx.x >> 5;
  const float* S = srcs[m];
  #pragma unroll
  for (int rr=0; rr<32; rr+=8)
    tile[ty+rr][tx] = S[(size_t)(kt*32+ty+rr)*N + nt*32+tx];
  __syncthreads();
  __bf16* D = ws + offs[m];
  #pragma unroll
  for (int rr=0; rr<32; rr+=8)
    D[(size_t)(nt*32+ty+rr)*K + kt*32+tx] = (__bf16)tile[tx][ty+rr];
}

// gelu(x) = x * sigmoid(2t),  t = 0.79788456(x + 0.044715 x^3)  (exact tanh form)
__device__ __forceinline__ float gelu_f(float x){
  float t = x * fmaf(0.0356774081f, x*x, 0.7978845608f);
  float u = __builtin_amdgcn_exp2f(-2.885390082f * t);
  return x * __builtin_amdgcn_rcpf(1.0f + u);
}

__device__ __forceinline__ void load16f(const __bf16* p, float* f){
  v8bf a = *(const v8bf*)p, b = *(const v8bf*)(p+8);
  #pragma unroll
  for (int i=0;i<8;i++){ f[i]=(float)a[i]; f[8+i]=(float)b[i]; }
}

// Weight fragments for NTPW n-tiles x KT k-chunks, held in registers.
template<int KT,int NTPW> struct WF { v8bf v[NTPW*KT]; };

template<int KT,int NTPW>
__device__ __forceinline__ WF<KT,NTPW> loadW(const __bf16* __restrict__ Wt,
                                             int wv, int lane){
  WF<KT,NTPW> w;
  const int ar=lane&15, quad=lane>>4;
  #pragma unroll
  for (int ln=0; ln<NTPW; ln++){
    const __bf16* wp = Wt + (size_t)((wv*NTPW+ln)*16+ar)*(KT*32) + quad*8;
    #pragma unroll
    for (int kt=0;kt<KT;kt++) w.v[ln*KT+kt] = *(const v8bf*)(wp + kt*32);
  }
  return w;
}

// N-split compute: D rows mt*16+ar, cols (wv*NTPW+ln)*16 + quad*4 + {0..3}.
template<int KT,int MT,int NTPW,typename LA,typename E>
__device__ __forceinline__ void gemmC(const WF<KT,NTPW>& wf,
    const float* __restrict__ bias, int wv, int lane, LA la, E epi)
{
  const int ar=lane&15, quad=lane>>4;
  #pragma unroll
  for (int ln=0; ln<NTPW; ln++){
    const int wt = wv*NTPW + ln;
    float4 b4 = *(const float4*)(bias + wt*16 + quad*4);
    #pragma unroll
    for (int mt=0; mt<MT; mt++){
      v4f c; c[0]=b4.x; c[1]=b4.y; c[2]=b4.z; c[3]=b4.w;
      #pragma unroll
      for (int kt=0;kt<KT;kt++)
        c = __builtin_amdgcn_mfma_f32_16x16x32_bf16(wf.v[ln*KT+kt], la(mt,kt,ar,quad), c, 0,0,0);
      epi(wt*16 + quad*4, mt, ar, c);
    }
  }
}

// LDS map (bytes), total 53120 <= 53248 (proven 3 blocks/CU) — same as round 9.
__global__ __launch_bounds__(256,3)
void swarm_mfma(P a, const __bf16* __restrict__ ws, int ntok)
{
  __shared__ char smem[53120] __attribute__((aligned(16)));
  __bf16* Ab   = (__bf16*)(smem);
  __bf16* Bb   = (__bf16*)(smem+17408);
  float*  TOKIN= (float*) (smem+17408);
  __bf16* Tk   = (__bf16*)(smem+34816);
  float*  OBSf = (float*) (smem+34816);
  __bf16* Po   = (__bf16*)(smem+34816);
  __bf16* Pe   = (__bf16*)(smem+44032);
  __bf16* Eg   = (__bf16*)(smem+46080);
  __bf16* Ru   = (__bf16*)(smem+47360);
  __bf16* mfb  = (__bf16*)(smem+48096);
  __bf16* msfb = (__bf16*)(smem+48224);
  float*  many = (float*) (smem+48352);
  float*  lga  = (float*) (smem+48416);
  __bf16* ECX  = (__bf16*)(smem+48672);
  float*  pattn= (float*) (smem+48672);
  __bf16* ATTb = (__bf16*)(smem+50720);
  __bf16* Cc   = (__bf16*)(smem+50720);

  const int lane = threadIdx.x & 63;
  const int wv   = threadIdx.x >> 6;
  const int ar   = lane & 15, quad = lane >> 4;
  const long blkT0 = (long)blockIdx.x*12;

  // ================= setup (wave-local tokens 3wv..3wv+2) =================
  for (int it=lane; it<3*117; it+=64){
    int tg=it/117, c=it-tg*117;
    long gt = blkT0 + 3*wv + tg; if (gt>ntok-1) gt=ntok-1;
    OBSf[(3*wv+tg)*120+c] = a.obs[gt*DOBS+c];
  }
  float* Df = (float*)Ab;
  for (int it=lane; it<75; it+=64){
    int tg=it/25, p=it-tg*25, i=p/5, j=p-i*5;
    const float* ob = OBSf + (3*wv+tg)*120 + 32;
    float d2=0.f;
    #pragma unroll
    for (int d=0;d<3;d++){
      float ri=ob[15*i+d]; ri = isfinite(ri)?ri:0.f;
      float rj=ob[15*j+d]; rj = isfinite(rj)?rj:0.f;
      float df=ri-rj; d2 += df*df;
    }
    Df[(3*wv+tg)*32+p]=sqrtf(d2);
  }
  if (lane<15){
    int T=3*wv+lane/5, s=lane%5;
    const float* b = OBSf + T*120 + 32 + 15*s;
    mfb[15*wv+lane] = (__bf16)((fabsf(b[0])>1e-6f||fabsf(b[1])>1e-6f||fabsf(b[2])>1e-6f)?1.f:0.f);
  }
  if (wv==0 && lane>=60){ mfb[lane]=(__bf16)0.f; msfb[lane]=(__bf16)0.f; }
  if (wv==0 && lane>=12 && lane<16) many[lane]=0.f;
  if (lane<3){
    int T=3*wv+lane;
    float any = (float)mfb[T*5]+(float)mfb[T*5+1]+(float)mfb[T*5+2]+(float)mfb[T*5+3]+(float)mfb[T*5+4];
    float anyf = (any>0.f)?1.f:0.f; many[T]=anyf;
    #pragma unroll
    for (int i=0;i<5;i++) msfb[T*5+i] = (anyf>0.f)? mfb[T*5+i] : (__bf16)((i==0)?1.f:0.f);
  }
  if (lane<15){
    int T=3*wv+lane/5, i=lane%5, R=15*wv+lane;
    float dmin=1e9f,dsum=0.f,cnt=0.f;
    #pragma unroll
    for (int j=0;j<5;j++){
      if (j!=i && (float)mfb[T*5+i]>0.5f && (float)mfb[T*5+j]>0.5f){
        float dd=Df[T*32+i*5+j];
        dmin=fminf(dmin,dd); dsum+=dd; cnt+=1.f;
      }
    }
    TOKIN[R*12+10]=dmin;
    TOKIN[R*12+11]=(cnt>0.f)? dsum/(cnt+1e-9f) : 0.f;
  }
  for (int it=lane; it<150; it+=64){
    int tg=it/50, q=it-tg*50, s=q/10, c=q-s*10;
    int T=3*wv+tg;
    const float* b = OBSf + T*120 + 32 + 15*s;
    float v;
    if (c<4)        v=b[11+c];
    else if (c==4)  v=b[9];
    else if (c==5)  v=b[10];
    else if (c<9)   v=b[6+(c-6)];
    else { float a0=b[6],a1=b[7],a2=b[8]; v=sqrtf(a0*a0+a1*a1+a2*a2); }
    TOKIN[(T*5+s)*12+c]=v;
  }
  for (int it=lane; it<96; it+=64){
    int tg=it>>5, c=it&31;
    Eg[(3*wv+tg)*40+c] = (__bf16)OBSf[(3*wv+tg)*120+c];
  }
  for (int it=lane; it<90; it+=64){
    int tg=it/30, c=it-tg*30;
    Ru[(3*wv+tg)*30+c] = (__bf16)OBSf[(3*wv+tg)*120+32+15*(c/6)+(c%6)];
  }
  for (int it=lane; it<192; it+=64){
    int tg=it>>6, c=it&63;
    float acc = a.pr_b[c];
    #pragma unroll
    for (int k=0;k<10;k++) acc += OBSf[(3*wv+tg)*120+107+k]*a.pr_w[k*64+c];
    Pe[(3*wv+tg)*64+c] = (__bf16)gelu_f(acc);
  }
  __syncthreads();   // S0

  // ==== P1: tok embed + ln1 ; PREFETCH QKV weights ====
  WF<2,1> wfK = loadW<2,1>(ws+W_A1K, wv, lane);
  WF<2,1> wfV = loadW<2,1>(ws+W_A1V, wv, lane);
  WF<2,1> wfQ = loadW<2,1>(ws+W_A1Q, wv, lane);
  {
    float w0[12];
    #pragma unroll
    for (int k=0;k<12;k++) w0[k] = a.tok_w[k*64+lane];
    float tb = a.tok_b[lane];
    for (int r=0;r<15;r++){
      int R = 15*wv + r;
      const float4* tin = (const float4*)(TOKIN + R*12);
      float4 x0 = tin[0], x1 = tin[1], x2 = tin[2];
      float acc = tb;
      acc=fmaf(x0.x,w0[0],acc); acc=fmaf(x0.y,w0[1],acc);
      acc=fmaf(x0.z,w0[2],acc); acc=fmaf(x0.w,w0[3],acc);
      acc=fmaf(x1.x,w0[4],acc); acc=fmaf(x1.y,w0[5],acc);
      acc=fmaf(x1.z,w0[6],acc); acc=fmaf(x1.w,w0[7],acc);
      acc=fmaf(x2.x,w0[8],acc); acc=fmaf(x2.y,w0[9],acc);
      acc=fmaf(x2.z,w0[10],acc); acc=fmaf(x2.w,w0[11],acc);
      Tk[R*72+lane] = (__bf16)(gelu_f(acc)*(float)mfb[R]);
    }
  }
  if (ar<15){   // ln1
    int R = 15*wv + ar;
    float x[16]; load16f(Tk + R*72 + quad*16, x);
    float s=0.f;
    #pragma unroll
    for (int i=0;i<16;i++) s += x[i];
    s += __shfl_xor(s,16,64); s += __shfl_xor(s,32,64);
    float m = s*(1.f/64.f), q=0.f;
    #pragma unroll
    for (int i=0;i<16;i++){ float d=x[i]-m; q=fmaf(d,d,q); }
    q += __shfl_xor(q,16,64); q += __shfl_xor(q,32,64);
    float rs = __builtin_amdgcn_rsqf(q*(1.f/64.f)+1e-6f);
    v8bf o0,o1;
    #pragma unroll
    for (int i=0;i<8;i++){
      o0[i]=(__bf16)((x[i]  -m)*rs*a.ln1_s[quad*16+i]  +a.ln1_b[quad*16+i]);
      o1[i]=(__bf16)((x[8+i]-m)*rs*a.ln1_s[quad*16+8+i]+a.ln1_b[quad*16+8+i]);
    }
    *(v8bf*)(Ab+R*136+quad*16)=o0; *(v8bf*)(Ab+R*136+quad*16+8)=o1;
  }
  __syncthreads();   // S1

  auto actAb = [&](int mt,int kt,int r,int q){ return *(const v8bf*)(Ab + (size_t)(mt*16+r)*136 + q*8 + kt*32); };
  auto actBb = [&](int mt,int kt,int r,int q){ return *(const v8bf*)(Bb + (size_t)(mt*16+r)*136 + q*8 + kt*32); };
  auto actTk = [&](int mt,int kt,int r,int q){ return *(const v8bf*)(Tk + (size_t)(mt*16+r)*72  + q*8 + kt*32); };

  // ==== P2: QKV ; PREFETCH o-proj ====
  WF<2,1> wfO = loadW<2,1>(ws+W_A1O, wv, lane);
  gemmC<2,4,1>(wfK, a.a1_kb, wv, lane, actAb,
    [&](int wb,int mt,int r,v4f c){ v4bf o;
      #pragma unroll
      for (int k=0;k<4;k++) o[k]=(__bf16)c[k];
      *(v4bf*)&Bb[(mt*16+r)*136+64+wb]=o; });
  gemmC<2,4,1>(wfV, a.a1_vb, wv, lane, actAb,
    [&](int wb,int mt,int r,v4f c){ v4bf o;
      #pragma unroll
      for (int k=0;k<4;k++) o[k]=(__bf16)c[k];
      *(v4bf*)&Ab[(mt*16+r)*136+64+wb]=o; });
  gemmC<2,4,1>(wfQ, a.a1_qb, wv, lane, actAb,
    [&](int wb,int mt,int r,v4f c){ v4bf o;
      #pragma unroll
      for (int k=0;k<4;k++) o[k]=(__bf16)c[k];
      *(v4bf*)&Bb[(mt*16+r)*136+wb]=o; });
  __syncthreads();   // S2

  // ==== P3: attn glue ; PREFETCH m1 ====
  WF<2,2> wfM1 = loadW<2,2>(ws+W_M1, wv, lane);
  if (lane<60){
    int tg=lane/20, rem=lane-tg*20, h=rem/5, i=rem-h*5;
    int T=3*wv+tg;
    bool mi = (float)msfb[T*5+i]>0.5f;
    float qv[16]; load16f(&Bb[(T*5+i)*136 + h*16], qv);
    float lgv[5], mx=NEG_INF_F;
    #pragma unroll
    for (int j=0;j<5;j++){
      float kk[16]; load16f(&Bb[(T*5+j)*136 + 64 + h*16], kk);
      float d=0.f;
      #pragma unroll
      for (int dd=0;dd<16;dd++) d += qv[dd]*kk[dd];
      bool mj = (float)msfb[T*5+j]>0.5f;
      lgv[j] = (mi&&mj)? d*0.25f : NEG_INF_F;
      mx = fmaxf(mx,lgv[j]);
    }
    float sum=0.f, ex[5];
    #pragma unroll
    for (int j=0;j<5;j++){ ex[j]=__expf(lgv[j]-mx); sum+=ex[j]; }
    float inv=1.0f/sum;
    #pragma unroll
    for (int j=0;j<5;j++) ATTb[T*100+(h*5+i)*5+j]=(__bf16)(ex[j]*inv);
  }
  {
    int h = lane>>4;
    #pragma unroll
    for (int tg=0; tg<3; tg++){
      int T=3*wv+tg;
      float v5[5];
      #pragma unroll
      for (int j=0;j<5;j++) v5[j] = (float)Ab[(T*5+j)*136+64+lane];
      #pragma unroll
      for (int i=0;i<5;i++){
        float o=0.f;
        #pragma unroll
        for (int j=0;j<5;j++) o += (float)ATTb[T*100+(h*5+i)*5+j]*v5[j];
        Ab[(T*5+i)*136+lane]=(__bf16)o;
      }
    }
  }
  __syncthreads();   // S3

  // ==== P4: o-proj + residual -> Tk ; PREFETCH m2 ====
  WF<4,2> wfM2 = loadW<4,2>(ws+W_M2, wv, lane);
  gemmC<2,4,1>(wfO, a.a1_ob, wv, lane, actAb,
    [&](int wb,int mt,int r,v4f c){
      int R=mt*16+r; float mm=(float)mfb[R];
      v4bf old=*(const v4bf*)&Tk[R*72+wb]; v4bf o;
      #pragma unroll
      for (int k=0;k<4;k++) o[k]=(__bf16)((float)old[k]+c[k]*mm);
      *(v4bf*)&Tk[R*72+wb]=o; });
  __syncthreads();   // S4

  // ==== P5: ln2 ; PREFETCH m3 + e1 ====
  WF<4,1> wfM3 = loadW<4,1>(ws+W_M3, wv, lane);
  WF<1,2> wfE1 = loadW<1,2>(ws+W_E1, wv, lane);
  if (ar<15){
    int R = 15*wv + ar;
    float x[16]; load16f(Tk + R*72 + quad*16, x);
    float s=0.f;
    #pragma unroll
    for (int i=0;i<16;i++) s += x[i];
    s += __shfl_xor(s,16,64); s += __shfl_xor(s,32,64);
    float m = s*(1.f/64.f), q=0.f;
    #pragma unroll
    for (int i=0;i<16;i++){ float d=x[i]-m; q=fmaf(d,d,q); }
    q += __shfl_xor(q,16,64); q += __shfl_xor(q,32,64);
    float rs = __builtin_amdgcn_rsqf(q*(1.f/64.f)+1e-6f);
    v8bf o0,o1;
    #pragma unroll
    for (int i=0;i<8;i++){
      o0[i]=(__bf16)((x[i]  -m)*rs*a.ln2_s[quad*16+i]  +a.ln2_b[quad*16+i]);
      o1[i]=(__bf16)((x[8+i]-m)*rs*a.ln2_s[quad*16+8+i]+a.ln2_b[quad*16+8+i]);
    }
    *(v8bf*)(Ab+R*136+quad*16)=o0; *(v8bf*)(Ab+R*136+quad*16+8)=o1;
  }
  __syncthreads();   // S5

  // ==== P6: m1 -> Bb ; PREFETCH e2 ====
  WF<4,2> wfE2 = loadW<4,2>(ws+W_E2, wv, lane);
  gemmC<2,4,2>(wfM1, a.m1_b, wv, lane, actAb,
    [&](int wb,int mt,int r,v4f c){ v4bf o;
      #pragma unroll
      for (int k=0;k<4;k++) o[k]=(__bf16)gelu_f(c[k]);
      *(v4bf*)&Bb[(mt*16+r)*136+wb]=o; });
  __syncthreads();   // S6

  // ==== P7: m2 -> Ab ; PREFETCH e3 ====
  WF<4,1> wfE3 = loadW<4,1>(ws+W_E3, wv, lane);
  gemmC<4,4,2>(wfM2, a.m2_b, wv, lane, actBb,
    [&](int wb,int mt,int r,v4f c){ v4bf o;
      #pragma unroll
      for (int k=0;k<4;k++) o[k]=(__bf16)gelu_f(c[k]);
      *(v4bf*)&Ab[(mt*16+r)*136+wb]=o; });
  __syncthreads();   // S7

  // ==== P8: m3 -> Tk ; e1 -> Bb rows 0..15 ; PREFETCH l1 ====
  WF<4,2> wfL1 = loadW<4,2>(ws+W_L1, wv, lane);
  gemmC<4,4,1>(wfM3, a.m3_b, wv, lane, actAb,
    [&](int wb,int mt,int r,v4f c){
      int R=mt*16+r; float mm=(float)mfb[R];
      v4bf old=*(const v4bf*)&Tk[R*72+wb]; v4bf o;
      #pragma unroll
      for (int k=0;k<4;k++) o[k]=(__bf16)(((float)old[k]+c[k]*mm)*mm);
      *(v4bf*)&Tk[R*72+wb]=o; });
  gemmC<1,1,2>(wfE1, a.e1_b, wv, lane,
    [&](int,int,int r,int q){ return *(const v8bf*)(Eg + (size_t)r*40 + q*8); },
    [&](int wb,int mt,int r,v4f c){ v4bf o;
      #pragma unroll
      for (int k=0;k<4;k++) o[k]=(__bf16)gelu_f(c[k]);
      *(v4bf*)&Bb[r*136+wb]=o; });
  __syncthreads();   // S8

  // ==== P9: e2 -> Ab rows 0..15 ; PREFETCH l2 ====
  WF<4,2> wfL2 = loadW<4,2>(ws+W_L2, wv, lane);
  gemmC<4,1,2>(wfE2, a.e2_b, wv, lane, actBb,
    [&](int wb,int mt,int r,v4f c){ v4bf o;
      #pragma unroll
      for (int k=0;k<4;k++) o[k]=(__bf16)gelu_f(c[k]);
      *(v4bf*)&Ab[r*136+wb]=o; });
  __syncthreads();   // S9

  // ==== P10: e3 -> ECX ; PREFETCH pk/pv ====
  WF<2,1> wfPK = loadW<2,1>(ws+W_PK, wv, lane);
  WF<2,1> wfPV = loadW<2,1>(ws+W_PV, wv, lane);
  gemmC<4,1,1>(wfE3, a.e3_b, wv, lane, actAb,
    [&](int wb,int mt,int r,v4f c){ v4bf o;
      #pragma unroll
      for (int k=0;k<4;k++) o[k]=(__bf16)c[k];
      *(v4bf*)&ECX[r*64+wb]=o; });
  __syncthreads();   // S10

  // ==== P11: l1 -> Bb ====
  gemmC<4,4,2>(wfL1, a.l1_b, wv, lane,
    [&](int mt,int kt,int r,int q){
      int R=mt*16+r;
      return (kt<2) ? *(const v8bf*)(Tk + (size_t)R*72 + q*8 + kt*32)
                    : *(const v8bf*)(ECX + (size_t)((R*205)>>10)*64 + q*8 + (kt-2)*32); },
    [&](int wb,int mt,int r,v4f c){ v4bf o;
      #pragma unroll
      for (int k=0;k<4;k++) o[k]=(__bf16)gelu_f(c[k]);
      *(v4bf*)&Bb[(mt*16+r)*136+wb]=o; });
  __syncthreads();   // S11

  // ==== P12: l2 -> Ab ; PREFETCH p_ow ====
  WF<2,1> wfPO = loadW<2,1>(ws+W_PO, wv, lane);
  gemmC<4,4,2>(wfL2, a.l2_b, wv, lane, actBb,
    [&](int wb,int mt,int r,v4f c){ v4bf o;
      #pragma unroll
      for (int k=0;k<4;k++) o[k]=(__bf16)gelu_f(c[k]);
      *(v4bf*)&Ab[(mt*16+r)*136+wb]=o; });
  __syncthreads();   // S12

  // ==== P13: l3 + alpha + v_r/v_u ; kp/vp -> Bb ====
  if (ar<15){
    int R = 15*wv + ar;
    float x[16], y[16];
    load16f(&Ab[R*136 + quad*32], x);
    load16f(&Ab[R*136 + quad*32 + 16], y);
    const float* w = a.l3_w + quad*32;
    float p = 0.f;
    #pragma unroll
    for (int i=0;i<16;i++) p = fmaf(x[i], w[i], p);
    #pragma unroll
    for (int i=0;i<16;i++) p = fmaf(y[i], w[16+i], p);
    p += __shfl_xor(p,16,64); p += __shfl_xor(p,32,64);
    if (quad==0) lga[R] = p + a.l3_b[0];
  }
  gemmC<2,4,1>(wfPK, a.p_kb, wv, lane, actTk,
    [&](int wb,int mt,int r,v4f c){ v4bf o;
      #pragma unroll
      for (int k=0;k<4;k++) o[k]=(__bf16)c[k];
      *(v4bf*)&Bb[(mt*16+r)*136+wb]=o; });
  gemmC<2,4,1>(wfPV, a.p_vb, wv, lane, actTk,
    [&](int wb,int mt,int r,v4f c){ v4bf o;
      #pragma unroll
      for (int k=0;k<4;k++) o[k]=(__bf16)c[k];
      *(v4bf*)&Bb[(mt*16+r)*136+64+wb]=o; });
  if (lane<3){
    int T=3*wv+lane;
    float ml[5], mx=-1e9f;
    #pragma unroll
    for (int i=0;i<5;i++){ ml[i]=((float)mfb[T*5+i]>0.5f)? lga[T*5+i] : -1e9f; mx=fmaxf(mx,ml[i]); }
    float den=0.f, e[5];
    #pragma unroll
    for (int i=0;i<5;i++){ e[i]=__expf(ml[i]-mx)*(float)mfb[T*5+i]; den+=e[i]; }
    float inv=1.0f/(den+1e-9f);
    #pragma unroll
    for (int i=0;i<5;i++) lga[T*5+i]=e[i]*inv;
  }
  if (lane<18){
    int tg=lane/6, c=lane-tg*6;
    int T=3*wv+tg;
    float v=0.f;
    #pragma unroll
    for (int i=0;i<5;i++) v += lga[T*5+i]*(float)Ru[T*30+i*6+c];
    long tk = blkT0 + T;
    if (tk<ntok) a.out[tk*134+128+c]=v;
  }
  __syncthreads();   // S13

  // ==== P14: pooling attn + pooled-o -> Po ; PREFETCH h1 ====
  WF<5,2> wfH1 = loadW<5,2>(ws+W_H1, wv, lane);
  if (lane<12){
    const float* qg = (const float*)(ws + W_QP);
    int tg=lane>>2, h=lane&3;
    int T=3*wv+tg;
    float qv[16];
    #pragma unroll
    for (int dd=0;dd<16;dd++) qv[dd]=qg[h*16+dd];
    float lgv[5], mx=NEG_INF_F;
    #pragma unroll
    for (int j=0;j<5;j++){
      float kk[16]; load16f(&Bb[(T*5+j)*136 + h*16], kk);
      float d=0.f;
      #pragma unroll
      for (int dd=0;dd<16;dd++) d += qv[dd]*kk[dd];
      lgv[j] = ((float)msfb[T*5+j]>0.5f)? d*0.25f : NEG_INF_F;
      mx = fmaxf(mx,lgv[j]);
    }
    float sum=0.f, ex[5];
    #pragma unroll
    for (int j=0;j<5;j++){ ex[j]=__expf(lgv[j]-mx); sum+=ex[j]; }
    float inv=1.0f/sum;
    #pragma unroll
    for (int j=0;j<5;j++) pattn[T*20+h*5+j]=ex[j]*inv;
  }
  for (int it=lane; it<192; it+=64){
    int tg=it>>6, c=it&63, h=c>>4;
    int T=3*wv+tg;
    float o=0.f;
    #pragma unroll
    for (int j=0;j<5;j++)
      o += pattn[T*20+h*5+j]*(float)Bb[(T*5+j)*136+64+c];
    Po[T*64+c]=(__bf16)o;
  }
  __syncthreads();   // S14

  // ==== P15: p_ow -> Cc ; PREFETCH h2 ====
  WF<4,2> wfH2 = loadW<4,2>(ws+W_H2, wv, lane);
  gemmC<2,1,1>(wfPO, a.p_ob, wv, lane,
    [&](int,int kt,int r,int q){ return *(const v8bf*)(Po + (size_t)r*64 + q*8 + kt*32); },
    [&](int wb,int mt,int r,v4f c){
      float mm = many[r];
      v4bf o;
      #pragma unroll
      for (int k=0;k<4;k++) o[k]=(__bf16)(c[k]*mm);
      *(v4bf*)&Cc[r*64+wb]=o; });
  __syncthreads();   // S15

  // ==== P16: h1 -> Bb rows 0..15 ; PREFETCH h3 ====
  WF<4,2> wfH3 = loadW<4,2>(ws+W_H3, wv, lane);
  gemmC<5,1,2>(wfH1, a.h1_b, wv, lane,
    [&](int,int kt,int r,int q){
      if (kt==0) return *(const v8bf*)(Eg + (size_t)r*40 + q*8);
      if (kt<3)  return *(const v8bf*)(Cc + (size_t)r*64 + q*8 + (kt-1)*32);
      return *(const v8bf*)(Pe + (size_t)r*64 + q*8 + (kt-3)*32); },
    [&](int wb,int mt,int r,v4f c){ v4bf o;
      #pragma unroll
      for (int k=0;k<4;k++) o[k]=(__bf16)gelu_f(c[k]);
      *(v4bf*)&Bb[r*136+wb]=o; });
  __syncthreads();   // S16

  // ==== P17: h2 -> Ab rows 0..15 ====
  gemmC<4,1,2>(wfH2, a.h2_b, wv, lane, actBb,
    [&](int wb,int mt,int r,v4f c){ v4bf o;
      #pragma unroll
      for (int k=0;k<4;k++) o[k]=(__bf16)gelu_f(c[k]);
      *(v4bf*)&Ab[r*136+wb]=o; });
  __syncthreads();   // S17

  // ==== P18: h3 -> out ====
  gemmC<4,1,2>(wfH3, a.h3_b, wv, lane, actAb,
    [&](int wb,int mt,int r,v4f c){
      long tk = blkT0 + r;
      if (r<12 && tk<ntok){
        float2* o2 = (float2*)&a.out[tk*134 + wb];
        o2[0] = make_float2(c[0], c[1]);
        o2[1] = make_float2(c[2], c[3]);
      } });
}

extern "C" void kernel_launch(void* const* d_in, const int* in_sizes, int n_in,
                              void* d_out, int out_size, void* d_ws, size_t ws_size,
                              hipStream_t stream)
{
  P a;
  const float** pp = reinterpret_cast<const float**>(&a);
  for (int i=0;i<50;i++) pp[i] = reinterpret_cast<const float*>(d_in[i]);
  a.out = reinterpret_cast<float*>(d_out);
  int ntok = in_sizes[0] / DOBS;   // 65536

  __bf16* ws = reinterpret_cast<__bf16*>(d_ws);
  hipLaunchKernelGGL(prep_w, dim3(173), dim3(256), 0, stream, a, ws);
  hipLaunchKernelGGL(swarm_mfma, dim3((ntok+11)/12), dim3(256), 0, stream, a, ws, ntok);
}